// Round 16
// baseline (15.732 us; speedup 1.0000x reference)
//
#include <hip/hip_runtime.h>

#define NB    64
#define NPT   8192
#define GSZ   128
#define TPB   1024
#define NBLK  256                     // 1 block/CU, 4 blocks per batch
#define ROWS  32                      // output stripe rows per block
#define NSCN  768                     // scanner threads (waves 0-11)

typedef float vf4 __attribute__((ext_vector_type(4)));

// Per-point permutohedral math. Bitwise-replicates XLA-CPU f32 (verified
// absmax == 0.0 rounds 1-15): pc = v*190.0f; elevated = E @ pc (FMA chain);
// u = rint(ev/3) via Markstein constant-division (bit-identical to IEEE /3,
// HW-verified R11); round-half-even; exact integer fixup.
__device__ __forceinline__ void compute_pt(float v0, float v1, float v2,
                                           int& u0o, int& u1o) {
    const float s6 = (float)2.449489742783178098197284074705891391989;
    const float ca = 2.0f / s6;
    const float cb = -1.0f / s6;
    const float y3 = 0.333333343267440796f;   // 0x3EAAAAAB = RN(1/3)
    float p0 = v0 * 190.0f;
    float p1 = v1 * 190.0f;
    float p2 = v2 * 190.0f;
    float ev0 = __builtin_fmaf(cb, p2, __builtin_fmaf(cb, p1, ca * p0));
    float ev1 = __builtin_fmaf(cb, p2, __builtin_fmaf(ca, p1, cb * p0));
    float ev2 = __builtin_fmaf(ca, p2, __builtin_fmaf(cb, p1, cb * p0));
    float t0 = ev0 * y3, t1 = ev1 * y3, t2 = ev2 * y3;
    float q0 = __builtin_fmaf(__builtin_fmaf(-3.0f, t0, ev0), y3, t0);
    float q1 = __builtin_fmaf(__builtin_fmaf(-3.0f, t1, ev1), y3, t1);
    float q2 = __builtin_fmaf(__builtin_fmaf(-3.0f, t2, ev2), y3, t2);
    float rg0 = rintf(q0), rg1 = rintf(q1), rg2 = rintf(q2);  // half-even
    int u0 = (int)rg0, u1 = (int)rg1, u2 = (int)rg2;
    float e0 = ev0 - rg0 * 3.0f;   // exact (moderate range)
    float e1 = ev1 - rg1 * 3.0f;
    float e2 = ev2 - rg2 * 3.0f;
    int rk0 = (int)(e1 > e0) + (int)(e2 > e0);
    int rk1 = (int)(e0 >= e1) + (int)(e2 > e1);   // (>)+(==) folded
    int rs = u0 + u1 + u2;
    if (rs > 0) {
        if (rk0 >= 3 - rs) u0 -= 1;
        if (rk1 >= 3 - rs) u1 -= 1;
    } else if (rs < 0) {
        if (rk0 < -rs) u0 += 1;
        if (rk1 < -rs) u1 += 1;
    }
    u0o = u0; u1o = u1;
}

// One block per (batch, 32-row stripe). WAVE SPECIALIZATION (R12/13 lesson:
// same-wave store+load serializes on the mid-kernel vmcnt(0) drain):
//  waves 12-15: NT-zero own stripe, then barrier — their vmcnt(0) drain runs
//               concurrently with the scan on waves 0-11.
//  waves  0-11: scan ALL 8192 batch points (exact local batch-min, zero
//               inter-block deps), barrier, scatter ~3 survivors via global
//               atomics onto the (drained) zeroed stripe.
// Stripe is block-owned; barrier orders writer drains before scanner atomics.
__global__ __launch_bounds__(TPB, 4) void kone(const float* __restrict__ x,
                                               float* __restrict__ out) {
    const int wg = blockIdx.x;
    const int bid = ((wg & 7) << 5) | (wg >> 3);  // XCD co-location swizzle (perf only)
    const int b = bid >> 2, r = bid & 3;
    const int t = threadIdx.x;
    const int rlo = r * ROWS;
    float* ob = out + (size_t)b * 3 * GSZ * GSZ + rlo * GSZ;
    const float* xb = x + (size_t)b * 6 * NPT;

    __shared__ int red0[12], red1[12];

    if (t >= NSCN) {
        // ---- writer waves (12-15): zero own stripe with NT stores ----
        const int tw = t - NSCN;   // 0..255
        const vf4 z4 = {0.f, 0.f, 0.f, 0.f};
#pragma unroll
        for (int k = 0; k < 12; ++k) {
            int idx = tw + (k << 8);            // 0..3071 float4s
            int c = idx >> 10, w = idx & 1023;  // plane, offset
            __builtin_nontemporal_store(z4, &((vf4*)(ob + c * GSZ * GSZ))[w]);
        }
        __syncthreads();   // per-wave vmcnt(0) drains OUR stores, overlapping scan
        return;
    }

    // ---- scanner waves (0-11): full-batch scan ----
    // chunks of 4 points: thread s owns chunks s, s+768, and (s<512) s+1536
    const int s = t;
    const bool third = (s < 512);              // waves 0-7 (wave-uniform)
    const int c0 = 4 * s, c1 = 4 * (s + 768), c2 = 4 * (s + 1536);

    const float4 A0 = *(const float4*)(xb + c0);
    const float4 A1 = *(const float4*)(xb + NPT + c0);
    const float4 A2 = *(const float4*)(xb + 2 * NPT + c0);
    const float4 B0 = *(const float4*)(xb + c1);
    const float4 B1 = *(const float4*)(xb + NPT + c1);
    const float4 B2 = *(const float4*)(xb + 2 * NPT + c1);
    float4 C0, C1, C2;
    if (third) {
        C0 = *(const float4*)(xb + c2);
        C1 = *(const float4*)(xb + NPT + c2);
        C2 = *(const float4*)(xb + 2 * NPT + c2);
    }

    int pk[12];
    int m0 = 0x7fffffff, m1 = 0x7fffffff;
    {
        const float* f0 = (const float*)&A0;
        const float* f1 = (const float*)&A1;
        const float* f2 = (const float*)&A2;
#pragma unroll
        for (int e = 0; e < 4; ++e) {
            int u0, u1;
            compute_pt(f0[e], f1[e], f2[e], u0, u1);
            m0 = min(m0, u0); m1 = min(m1, u1);
            pk[e] = (u0 & 0xffff) | (u1 << 16);
        }
    }
    {
        const float* f0 = (const float*)&B0;
        const float* f1 = (const float*)&B1;
        const float* f2 = (const float*)&B2;
#pragma unroll
        for (int e = 0; e < 4; ++e) {
            int u0, u1;
            compute_pt(f0[e], f1[e], f2[e], u0, u1);
            m0 = min(m0, u0); m1 = min(m1, u1);
            pk[4 + e] = (u0 & 0xffff) | (u1 << 16);
        }
    }
    if (third) {
        const float* f0 = (const float*)&C0;
        const float* f1 = (const float*)&C1;
        const float* f2 = (const float*)&C2;
#pragma unroll
        for (int e = 0; e < 4; ++e) {
            int u0, u1;
            compute_pt(f0[e], f1[e], f2[e], u0, u1);
            m0 = min(m0, u0); m1 = min(m1, u1);
            pk[8 + e] = (u0 & 0xffff) | (u1 << 16);
        }
    }
    for (int o = 32; o; o >>= 1) {
        m0 = min(m0, __shfl_down(m0, o));
        m1 = min(m1, __shfl_down(m1, o));
    }
    if ((t & 63) == 0) { red0[t >> 6] = m0; red1[t >> 6] = m1; }
    __syncthreads();   // writers' stores drained; minima published
    int off0 = red0[0], off1 = red1[0];
#pragma unroll
    for (int i = 1; i < 12; ++i) {
        off0 = min(off0, red0[i]);
        off1 = min(off1, red1[i]);
    }

    // scatter own-stripe survivors (~3/block) via global atomics
    const int nk = third ? 12 : 8;
#pragma unroll
    for (int k = 0; k < 12; ++k) {
        if (k >= nk) break;
        int p = pk[k];
        int u0 = (int)(short)(p & 0xffff);
        int u1 = p >> 16;
        int i = u0 - off0, j = u1 - off1;   // >= 0 always
        int il = i - rlo;
        if ((unsigned)il < ROWS && (unsigned)j < GSZ) {
            int n = (k < 4 ? c0 : (k < 8 ? c1 : c2)) + (k & 3);
            float* o = ob + (size_t)il * GSZ + j;
            atomicAdd(o + 0 * GSZ * GSZ, xb[3 * NPT + n]);
            atomicAdd(o + 1 * GSZ * GSZ, xb[4 * NPT + n]);
            atomicAdd(o + 2 * GSZ * GSZ, xb[5 * NPT + n]);
        }
    }
}

extern "C" void kernel_launch(void* const* d_in, const int* in_sizes, int n_in,
                              void* d_out, int out_size, void* d_ws, size_t ws_size,
                              hipStream_t stream) {
    const float* x = (const float*)d_in[0];
    float* out = (float*)d_out;
    kone<<<NBLK, TPB, 0, stream>>>(x, out);
}

// Round 17
// 12.169 us; speedup vs baseline: 1.2929x; 1.2929x over previous
//
#include <hip/hip_runtime.h>

#define NB    64
#define NPT   8192
#define GSZ   128
#define TPB   1024
#define BPB   4                       // blocks per batch
#define NBLK  (NB * BPB)              // 256 = 1 block/CU, full chip
#define ROWS  32                      // output stripe rows per block
#define TILE  (3 * ROWS * GSZ)        // 12288 floats = 48 KB LDS

typedef float vf4 __attribute__((ext_vector_type(4)));

// Per-point permutohedral math. Bitwise-replicates XLA-CPU f32 (verified
// absmax == 0.0 rounds 1-16): pc = v*190.0f; elevated = E @ pc (FMA chain);
// u = rint(ev/3) via Markstein constant-division (bit-identical to IEEE /3,
// HW-verified R11); round-half-even; exact integer fixup.
__device__ __forceinline__ void compute_pt(float v0, float v1, float v2,
                                           int& u0o, int& u1o) {
    const float s6 = (float)2.449489742783178098197284074705891391989;
    const float ca = 2.0f / s6;
    const float cb = -1.0f / s6;
    const float y3 = 0.333333343267440796f;   // 0x3EAAAAAB = RN(1/3)
    float p0 = v0 * 190.0f;
    float p1 = v1 * 190.0f;
    float p2 = v2 * 190.0f;
    float ev0 = __builtin_fmaf(cb, p2, __builtin_fmaf(cb, p1, ca * p0));
    float ev1 = __builtin_fmaf(cb, p2, __builtin_fmaf(ca, p1, cb * p0));
    float ev2 = __builtin_fmaf(ca, p2, __builtin_fmaf(cb, p1, cb * p0));
    float t0 = ev0 * y3, t1 = ev1 * y3, t2 = ev2 * y3;
    float q0 = __builtin_fmaf(__builtin_fmaf(-3.0f, t0, ev0), y3, t0);
    float q1 = __builtin_fmaf(__builtin_fmaf(-3.0f, t1, ev1), y3, t1);
    float q2 = __builtin_fmaf(__builtin_fmaf(-3.0f, t2, ev2), y3, t2);
    float rg0 = rintf(q0), rg1 = rintf(q1), rg2 = rintf(q2);  // half-even
    int u0 = (int)rg0, u1 = (int)rg1, u2 = (int)rg2;
    float e0 = ev0 - rg0 * 3.0f;   // exact (moderate range)
    float e1 = ev1 - rg1 * 3.0f;
    float e2 = ev2 - rg2 * 3.0f;
    int rk0 = (int)(e1 > e0) + (int)(e2 > e0);
    int rk1 = (int)(e0 >= e1) + (int)(e2 > e1);   // (>)+(==) folded
    int rs = u0 + u1 + u2;
    if (rs > 0) {
        if (rk0 >= 3 - rs) u0 -= 1;
        if (rk1 >= 3 - rs) u1 -= 1;
    } else if (rs < 0) {
        if (rk0 < -rs) u0 += 1;
        if (rk1 < -rs) u1 += 1;
    }
    u0o = u0; u1o = u1;
}

// R11 verbatim — best measured (11.44 µs). One block per (batch, 32-row
// output stripe). Scan ALL batch points (exact local batch-min, zero
// inter-block deps), accumulate own-stripe survivors in an LDS tile,
// write the tile once with nontemporal stores at kernel end (measured
// better than cached stores, R15; any earlier/interleaved store issue
// poisons the load queue, R12/R13/R16). No global atomics, no fences, no ws.
__global__ __launch_bounds__(TPB, 4) void kone(const float* __restrict__ x,
                                               float* __restrict__ out) {
    const int wg = blockIdx.x;
    const int bid = ((wg & 7) << 5) | (wg >> 3);  // XCD co-location swizzle (perf only)
    const int b = bid >> 2, r = bid & 3;
    const int t = threadIdx.x;

    __shared__ float tile[TILE];
    __shared__ int red0[16], red1[16], osh[2];

    // zero own LDS tile (3 ds_write_b128 per thread)
    float4* tile4 = (float4*)tile;
    const float4 z4 = make_float4(0.f, 0.f, 0.f, 0.f);
#pragma unroll
    for (int k = 0; k < TILE / 4 / TPB; ++k) tile4[t + k * TPB] = z4;

    // pass 1: all 8192 batch points; issue ALL 12 float4 position loads up
    // front (latency fully overlapped with compute), then exact local min.
    const float* xb = x + (size_t)b * 6 * NPT;
    const int n0 = 4 * t, n1 = 4 * t + 4096;
    const float4 A0 = *(const float4*)(xb + n0);
    const float4 A1 = *(const float4*)(xb + NPT + n0);
    const float4 A2 = *(const float4*)(xb + 2 * NPT + n0);
    const float4 B0 = *(const float4*)(xb + n1);
    const float4 B1 = *(const float4*)(xb + NPT + n1);
    const float4 B2 = *(const float4*)(xb + 2 * NPT + n1);

    int pk[8];
    int m0 = 0x7fffffff, m1 = 0x7fffffff;
    {
        const float* f0 = (const float*)&A0;
        const float* f1 = (const float*)&A1;
        const float* f2 = (const float*)&A2;
#pragma unroll
        for (int e = 0; e < 4; ++e) {
            int u0, u1;
            compute_pt(f0[e], f1[e], f2[e], u0, u1);
            m0 = min(m0, u0); m1 = min(m1, u1);
            pk[e] = (u0 & 0xffff) | (u1 << 16);
        }
    }
    {
        const float* f0 = (const float*)&B0;
        const float* f1 = (const float*)&B1;
        const float* f2 = (const float*)&B2;
#pragma unroll
        for (int e = 0; e < 4; ++e) {
            int u0, u1;
            compute_pt(f0[e], f1[e], f2[e], u0, u1);
            m0 = min(m0, u0); m1 = min(m1, u1);
            pk[4 + e] = (u0 & 0xffff) | (u1 << 16);
        }
    }
    for (int o = 32; o; o >>= 1) {
        m0 = min(m0, __shfl_down(m0, o));
        m1 = min(m1, __shfl_down(m1, o));
    }
    if ((t & 63) == 0) { red0[t >> 6] = m0; red1[t >> 6] = m1; }
    __syncthreads();
    if (t == 0) {
        int a0 = red0[0], a1 = red1[0];
#pragma unroll
        for (int i = 1; i < TPB / 64; ++i) { a0 = min(a0, red0[i]); a1 = min(a1, red1[i]); }
        osh[0] = a0; osh[1] = a1;
    }
    __syncthreads();
    const int off0 = osh[0], off1 = osh[1];
    const int rlo = r * ROWS;

    // pass 2: own-stripe survivors -> LDS atomics (sparse, ~1 per block)
#pragma unroll
    for (int k = 0; k < 8; ++k) {
        int p = pk[k];
        int u0 = (int)(short)(p & 0xffff);
        int u1 = p >> 16;
        int i = u0 - off0, j = u1 - off1;   // >= 0 always
        int il = i - rlo;
        if ((unsigned)il < ROWS && (unsigned)j < GSZ) {
            int n = 4 * t + (k >> 2) * 4096 + (k & 3);
            atomicAdd(&tile[0 * ROWS * GSZ + il * GSZ + j], xb[3 * NPT + n]);
            atomicAdd(&tile[1 * ROWS * GSZ + il * GSZ + j], xb[4 * NPT + n]);
            atomicAdd(&tile[2 * ROWS * GSZ + il * GSZ + j], xb[5 * NPT + n]);
        }
    }
    __syncthreads();

    // write own stripe once (nontemporal, fully coalesced; native vec type)
    float* ob = out + (size_t)b * 3 * GSZ * GSZ + rlo * GSZ;
    const vf4* tilev = (const vf4*)tile;
#pragma unroll
    for (int c = 0; c < 3; ++c)
        __builtin_nontemporal_store(tilev[c * 1024 + t], &((vf4*)(ob + c * GSZ * GSZ))[t]);
}

extern "C" void kernel_launch(void* const* d_in, const int* in_sizes, int n_in,
                              void* d_out, int out_size, void* d_ws, size_t ws_size,
                              hipStream_t stream) {
    const float* x = (const float*)d_in[0];
    float* out = (float*)d_out;
    kone<<<NBLK, TPB, 0, stream>>>(x, out);
}